// Round 6
// baseline (143.750 us; speedup 1.0000x reference)
//
#include <hip/hip_runtime.h>
#include <hip/hip_bf16.h>

// AxialAtten B=4,H=W=C=64. Two passes: Q=xW^T+b; K=Q; V=xWv^T+b;
// O = sigmoid(QK^T/8) V; x = O*scale + x (with axis transpose).
// Pass1: xh[b,n,d] = x[b*BHWC + d*4096 + n]            (n=w*64+c, d=h)
// Pass2: xw[b,n,d] = x[b*BHWC + (n>>6)*4096 + d*64 + (n&63)]  (d=w)
//
// Q is pre-scaled by ALPHA = sqrt(0.125*log2(e)) so that
// sigmoid(S/8) = rcp(1 + exp2(-S')) with S' = (alpha Q)(alpha K)^T.
//
// NOTE (round-5 post-mortem): hand-written `v_cvt_pk_bf16_f32` asm had
// swapped half semantics (absmax fingerprint = adjacent-k pair swap).
// Pack via __float2bfloat16 + shift/or; the compiler fuses this to the
// packed convert with correct semantics (guide m240).

typedef __attribute__((ext_vector_type(8)))  short        short8;   // 8 bf16
typedef __attribute__((ext_vector_type(16))) float        f32x16;
typedef __attribute__((ext_vector_type(4)))  unsigned int u32x4;
typedef __attribute__((ext_vector_type(2)))  unsigned int u32x2;
typedef __attribute__((ext_vector_type(4)))  float        f32x4;

#define BHWC (4096 * 64)
#define ALPHA 0.42466089f   // sqrt(0.125 * 1.44269504)

__device__ __forceinline__ unsigned short f2bf(float f) {
    __hip_bfloat16 h = __float2bfloat16(f);          // HW RNE conversion
    union { __hip_bfloat16 h; unsigned short u; } c; c.h = h;
    return c.u;
}
__device__ __forceinline__ f32x16 zero16() {
    f32x16 z;
    #pragma unroll
    for (int r = 0; r < 16; ++r) z[r] = 0.0f;
    return z;
}

// ---------------------------------------------------------------------------
// MFMA projection: Q[b][n][o] bf16 (pre-scaled by ALPHA) and V^T[b][o][n] bf16.
// grid 256 = 4b x 64 n-tiles, block 256 (4 waves: 2 for Q, 2 for V).
// ---------------------------------------------------------------------------
template<int MODE>
__global__ __launch_bounds__(256) void proj_kernel(
    const float* __restrict__ xsrc,
    const float* __restrict__ Wq, const float* __restrict__ Bq,
    const float* __restrict__ Wv, const float* __restrict__ Bv,
    unsigned short* __restrict__ Qo, unsigned short* __restrict__ VTo)
{
    __shared__ __align__(16) unsigned short xbf[64 * 64];      // [n][d] XOR-swizzled
    __shared__ __align__(16) unsigned short wbf[2][64 * 64];   // [o][d] XOR-swizzled
    __shared__ __align__(16) unsigned short vst[64 * 66];      // [o][n] V re-stage

    const int b = blockIdx.x >> 6, tile = blockIdx.x & 63, n0 = tile << 6;
    const int tid = threadIdx.x;
    const float* xb = xsrc + b * BHWC;

    for (int i = tid; i < 4096; i += 256) {
        const int d = i >> 6, nl = i & 63;
        float v;
        if (MODE == 0) v = xb[d * 4096 + n0 + nl];
        else           v = xb[tile * 4096 + i];          // = tile*4096 + d*64 + c
        xbf[nl * 64 + (d ^ ((nl & 7) << 3))] = f2bf(v);
        wbf[0][d * 64 + (nl ^ ((d & 7) << 3))] = f2bf(Wq[i] * ALPHA);  // fold alpha
        wbf[1][d * 64 + (nl ^ ((d & 7) << 3))] = f2bf(Wv[i]);
    }
    __syncthreads();

    const int wave = tid >> 6, lane = tid & 63, l31 = lane & 31, hi = lane >> 5;
    const int mat = wave >> 1, nc = wave & 1;
    const int o = nc * 32 + l31;

    short8 bw[4];
    #pragma unroll
    for (int dc = 0; dc < 4; ++dc)
        bw[dc] = *(const short8*)&wbf[mat][o * 64 + ((dc * 16 + hi * 8) ^ ((o & 7) << 3))];

    f32x16 acc[2]; acc[0] = zero16(); acc[1] = zero16();
    #pragma unroll
    for (int dc = 0; dc < 4; ++dc) {
        #pragma unroll
        for (int mc = 0; mc < 2; ++mc) {
            const int row = mc * 32 + l31;
            const short8 a = *(const short8*)&xbf[row * 64 + ((dc * 16 + hi * 8) ^ ((row & 7) << 3))];
            acc[mc] = __builtin_amdgcn_mfma_f32_32x32x16_bf16(a, bw[dc], acc[mc], 0, 0, 0);
        }
    }
    const float bias = mat ? Bv[o] : (Bq[o] * ALPHA);

    if (mat == 0) {
        unsigned short* Qb = Qo + b * BHWC;
        #pragma unroll
        for (int mc = 0; mc < 2; ++mc)
            #pragma unroll
            for (int reg = 0; reg < 16; ++reg) {
                const int n = n0 + mc * 32 + (reg & 3) + 8 * (reg >> 2) + 4 * hi;
                Qb[n * 64 + o] = f2bf(acc[mc][reg] + bias);
            }
    } else {
        #pragma unroll
        for (int mc = 0; mc < 2; ++mc)
            #pragma unroll
            for (int reg = 0; reg < 16; ++reg) {
                const int nl2 = mc * 32 + (reg & 3) + 8 * (reg >> 2) + 4 * hi;
                vst[o * 66 + nl2] = f2bf(acc[mc][reg] + bias);
            }
    }
    __syncthreads();
    {   // coalesced V^T writeback: 4 threads per o-row
        unsigned short* VTb = VTo + b * BHWC;
        const int oo = tid >> 2, seg = tid & 3;
        u32x4 t0, t1;
        #pragma unroll
        for (int j = 0; j < 4; ++j) {
            t0[j] = *(const unsigned int*)&vst[oo * 66 + seg * 16 + j * 2];
            t1[j] = *(const unsigned int*)&vst[oo * 66 + seg * 16 + 8 + j * 2];
        }
        *(u32x4*)(VTb + oo * 4096 + n0 + seg * 16)     = t0;
        *(u32x4*)(VTb + oo * 4096 + n0 + seg * 16 + 8) = t1;
    }
}

// ---------------------------------------------------------------------------
// Fused sigmoid-attention, 32x32 MFMA, P via per-wave-private LDS tiles.
// grid 256 = 4b x 64 m-tiles(64 rows); block 1024 = 16 waves =
// (msub in {0,1}) x (kq in {0..7}); wave tile = 32m x 512k, 8 iters of 64k.
// Barrier-free main loop; register-dieted to fit 128 (VGPR+AGPR) for
// 4 waves/SIMD: single kf/s set, vf+pf consumed in halves.
// ---------------------------------------------------------------------------
template<int MODE>
__global__ __launch_bounds__(1024, 4) void attn_kernel(
    const unsigned short* __restrict__ Q,    // [b][4096][64] bf16, alpha-scaled (= K)
    const unsigned short* __restrict__ VT,   // [b][64][4096] bf16
    const float* __restrict__ xres,
    const float* __restrict__ wsc,
    float* __restrict__ xout)
{
    // union: Ps (16 waves x 4KB, main loop) / Obuf (8 x 64x33 f32, reduce)
    __shared__ __align__(16) char smem[8 * 2112 * 4];   // 67584 B
    float* Obuf = (float*)smem;

    const int bid = ((int)blockIdx.x & 7) * 32 + ((int)blockIdx.x >> 3);
    const int b = bid >> 6, mt = bid & 63, m0 = mt << 6;
    const int tid = threadIdx.x, wave = tid >> 6, lane = tid & 63;
    const int l31 = lane & 31, hi = lane >> 5;
    const int msub = wave & 1, kq = wave >> 1;
    const unsigned short* Qb  = Q  + b * BHWC;
    const unsigned short* VTb = VT + b * BHWC;

    // this wave's 32x64 bf16 P tile; loop-invariant addresses
    char* const Pw   = smem + wave * 4096;
    const int  psw   = (l31 & 7) << 4;
    char* const wb   = Pw + l31 * 128 + 8 * hi;          // P write base (+ (64krc+16q)^psw)
    const char* pr0 = Pw + l31 * 128 + (( 0 + hi * 16) ^ psw);   // pf read addrs
    const char* pr1 = Pw + l31 * 128 + ((32 + hi * 16) ^ psw);
    const char* pr2 = Pw + l31 * 128 + ((64 + hi * 16) ^ psw);
    const char* pr3 = Pw + l31 * 128 + ((96 + hi * 16) ^ psw);

    // Q B-fragments (persistent): B[k=d][col=m]
    short8 qf[4];
    #pragma unroll
    for (int dc = 0; dc < 4; ++dc)
        qf[dc] = *(const short8*)(Qb + (m0 + msub * 32 + l31) * 64 + dc * 16 + hi * 8);

    f32x16 acc[2]; acc[0] = zero16(); acc[1] = zero16();   // O[32m][64d]

    // sigmoid(S/8)=rcp(1+exp2(-S')); pack regs 4q..4q+3 (consecutive kr) -> b64.
    // Pack via f2bf + shift/or (round-3/4-proven order; compiler fuses to cvt_pk).
    auto SIGSTORE = [&](const f32x16& s, int krc) {
        #pragma unroll
        for (int q = 0; q < 4; ++q) {
            const float p0 = __builtin_amdgcn_rcpf(1.0f + exp2f(-s[4 * q    ]));
            const float p1 = __builtin_amdgcn_rcpf(1.0f + exp2f(-s[4 * q + 1]));
            const float p2 = __builtin_amdgcn_rcpf(1.0f + exp2f(-s[4 * q + 2]));
            const float p3 = __builtin_amdgcn_rcpf(1.0f + exp2f(-s[4 * q + 3]));
            u32x2 pk;
            pk[0] = (unsigned int)f2bf(p0) | ((unsigned int)f2bf(p1) << 16);
            pk[1] = (unsigned int)f2bf(p2) | ((unsigned int)f2bf(p3) << 16);
            *(u32x2*)(wb + ((krc * 64 + 16 * q) ^ psw)) = pk;
        }
    };

    #pragma unroll 1
    for (int i = 0; i < 8; ++i) {
        const unsigned short* kt = Qb + (kq * 512 + i * 64) * 64;   // K tile base
        const unsigned short* vt = VTb + kq * 512 + i * 64;         // V^T tile base

        // ---- krc0: S^T[kr][m] = sum_d K[kr][d] Q[m][d] ----
        short8 kf[4];
        #pragma unroll
        for (int dc = 0; dc < 4; ++dc)
            kf[dc] = *(const short8*)(kt + l31 * 64 + dc * 16 + hi * 8);
        f32x16 s = zero16();
        #pragma unroll
        for (int dc = 0; dc < 4; ++dc)
            s = __builtin_amdgcn_mfma_f32_32x32x16_bf16(kf[dc], qf[dc], s, 0, 0, 0);
        SIGSTORE(s, 0);

        // ---- krc1 (reuse kf/s regs) ----
        #pragma unroll
        for (int dc = 0; dc < 4; ++dc)
            kf[dc] = *(const short8*)(kt + (32 + l31) * 64 + dc * 16 + hi * 8);
        s = zero16();
        #pragma unroll
        for (int dc = 0; dc < 4; ++dc)
            s = __builtin_amdgcn_mfma_f32_32x32x16_bf16(kf[dc], qf[dc], s, 0, 0, 0);

        // first vf half (kc 0,1) issued before SIGSTORE: L2 latency hides
        short8 vf00 = *(const short8*)(vt +       l31  * 4096 +  0 + hi * 8);
        short8 vf01 = *(const short8*)(vt + (32 + l31) * 4096 +  0 + hi * 8);
        short8 vf10 = *(const short8*)(vt +       l31  * 4096 + 16 + hi * 8);
        short8 vf11 = *(const short8*)(vt + (32 + l31) * 4096 + 16 + hi * 8);

        SIGSTORE(s, 1);

        // ---- PV first half: kc 0,1 ----
        short8 pf0 = *(const short8*)pr0;
        short8 pf1 = *(const short8*)pr1;
        acc[0] = __builtin_amdgcn_mfma_f32_32x32x16_bf16(pf0, vf00, acc[0], 0, 0, 0);
        acc[1] = __builtin_amdgcn_mfma_f32_32x32x16_bf16(pf0, vf01, acc[1], 0, 0, 0);
        acc[0] = __builtin_amdgcn_mfma_f32_32x32x16_bf16(pf1, vf10, acc[0], 0, 0, 0);
        acc[1] = __builtin_amdgcn_mfma_f32_32x32x16_bf16(pf1, vf11, acc[1], 0, 0, 0);

        // ---- PV second half: kc 2,3 (reuse vf/pf regs) ----
        vf00 = *(const short8*)(vt +       l31  * 4096 + 32 + hi * 8);
        vf01 = *(const short8*)(vt + (32 + l31) * 4096 + 32 + hi * 8);
        vf10 = *(const short8*)(vt +       l31  * 4096 + 48 + hi * 8);
        vf11 = *(const short8*)(vt + (32 + l31) * 4096 + 48 + hi * 8);
        pf0 = *(const short8*)pr2;
        pf1 = *(const short8*)pr3;
        acc[0] = __builtin_amdgcn_mfma_f32_32x32x16_bf16(pf0, vf00, acc[0], 0, 0, 0);
        acc[1] = __builtin_amdgcn_mfma_f32_32x32x16_bf16(pf0, vf01, acc[1], 0, 0, 0);
        acc[0] = __builtin_amdgcn_mfma_f32_32x32x16_bf16(pf1, vf10, acc[0], 0, 0, 0);
        acc[1] = __builtin_amdgcn_mfma_f32_32x32x16_bf16(pf1, vf11, acc[1], 0, 0, 0);
    }

    // ---- tree-reduce 8 kq-partials per msub through LDS (aliases Ps) ----
    __syncthreads();
    if (kq < 4) {
        float* Ob = Obuf + (msub * 4 + kq) * 2112;
        #pragma unroll
        for (int dc2 = 0; dc2 < 2; ++dc2)
            #pragma unroll
            for (int reg = 0; reg < 16; ++reg)
                Ob[(dc2 * 32 + l31) * 33 + (reg & 3) + 8 * (reg >> 2) + 4 * hi] = acc[dc2][reg];
    }
    __syncthreads();
    if (kq >= 4) {
        float* Ob = Obuf + (msub * 4 + kq - 4) * 2112;
        #pragma unroll
        for (int dc2 = 0; dc2 < 2; ++dc2)
            #pragma unroll
            for (int reg = 0; reg < 16; ++reg)
                Ob[(dc2 * 32 + l31) * 33 + (reg & 3) + 8 * (reg >> 2) + 4 * hi] += acc[dc2][reg];
    }
    __syncthreads();

    // ---- epilogue: sum 4 slots + residual; 1024 threads x 4 outputs ----
    const float w = wsc[0];
    const int d = tid >> 4, ms = (tid & 15) << 2;
    const int msb = ms >> 5, mloc = ms & 31;
    long base;
    if (MODE == 0) base = (long)b * BHWC + d * 4096 + m0 + ms;
    else           base = (long)b * BHWC + mt * 4096 + d * 64 + ms;
    const float* O0 = Obuf + (msb * 4 + 0) * 2112 + d * 33 + mloc;
    const float* O1 = Obuf + (msb * 4 + 1) * 2112 + d * 33 + mloc;
    const float* O2 = Obuf + (msb * 4 + 2) * 2112 + d * 33 + mloc;
    const float* O3 = Obuf + (msb * 4 + 3) * 2112 + d * 33 + mloc;
    f32x4 r = *(const f32x4*)(xres + base);
    f32x4 o;
    #pragma unroll
    for (int j = 0; j < 4; ++j)
        o[j] = (O0[j] + O1[j] + O2[j] + O3[j]) * w + r[j];
    *(f32x4*)(xout + base) = o;
}

// ---------------------------------------------------------------------------
extern "C" void kernel_launch(void* const* d_in, const int* in_sizes, int n_in,
                              void* d_out, int out_size, void* d_ws, size_t ws_size,
                              hipStream_t stream) {
    const float* x    = (const float*)d_in[0];
    const float* hq_w = (const float*)d_in[1];
    const float* hq_b = (const float*)d_in[2];
    const float* hv_w = (const float*)d_in[3];
    const float* hv_b = (const float*)d_in[4];
    const float* wq_w = (const float*)d_in[5];
    const float* wq_b = (const float*)d_in[6];
    const float* wv_w = (const float*)d_in[7];
    const float* wv_b = (const float*)d_in[8];
    const float* h_wt = (const float*)d_in[9];
    const float* w_wt = (const float*)d_in[10];
    float* out = (float*)d_out;

    unsigned short* Qws  = (unsigned short*)d_ws;          // 2MB (alpha-scaled Q)
    unsigned short* VTws = Qws + 4 * BHWC;                 // 2MB

    proj_kernel<0><<<256, 256, 0, stream>>>(x, hq_w, hq_b, hv_w, hv_b, Qws, VTws);
    attn_kernel<0><<<256, 1024, 0, stream>>>(Qws, VTws, x, h_wt, out);
    proj_kernel<1><<<256, 256, 0, stream>>>(out, wq_w, wq_b, wv_w, wv_b, Qws, VTws);
    attn_kernel<1><<<256, 1024, 0, stream>>>(Qws, VTws, out, w_wt, out);
}

// Round 7
// 98.377 us; speedup vs baseline: 1.4612x; 1.4612x over previous
//
#include <hip/hip_runtime.h>
#include <hip/hip_bf16.h>

// AxialAtten B=4,H=W=C=64. Two passes: Q=xW^T+b; K=Q; V=xWv^T+b;
// O = sigmoid(QK^T/8) V; x = O*scale + x (with axis transpose).
// Pass1: xh[b,n,d] = x[b*BHWC + d*4096 + n]            (n=w*64+c, d=h)
// Pass2: xw[b,n,d] = x[b*BHWC + (n>>6)*4096 + d*64 + (n&63)]  (d=w)
//
// Q pre-scaled by ALPHA = sqrt(0.125*log2(e)): sigmoid(S/8)=rcp(1+exp2(-S')).
//
// WORKSPACE LAYOUTS (fragment-major, so every attn wave-load is 1KB contiguous):
//   Qf: [b][rowblk(128)][dc(4)][hi(2)][l31(32)][e(8)]  (rowblk = n>>5)
//       element Q[n][d] at b*BHWC + (n>>5)*2048 + (d>>4)*512 + ((d>>3)&1)*256
//                         + (n&31)*8 + (d&7)
//   Vf: [b][d0(2)][kk(256)][hi(2)][l31(32)][e(8)]
//       element V^T[d][k] at b*BHWC + (d>>5)*131072 + (k>>4)*512 + ((k>>3)&1)*256
//                           + (d&31)*8 + (k&7)

typedef __attribute__((ext_vector_type(8)))  short        short8;   // 8 bf16
typedef __attribute__((ext_vector_type(16))) float        f32x16;
typedef __attribute__((ext_vector_type(4)))  unsigned int u32x4;
typedef __attribute__((ext_vector_type(2)))  unsigned int u32x2;
typedef __attribute__((ext_vector_type(4)))  float        f32x4;

#define BHWC (4096 * 64)
#define ALPHA 0.42466089f   // sqrt(0.125 * 1.44269504)

__device__ __forceinline__ unsigned short f2bf(float f) {
    __hip_bfloat16 h = __float2bfloat16(f);          // HW RNE conversion
    union { __hip_bfloat16 h; unsigned short u; } c; c.h = h;
    return c.u;
}
__device__ __forceinline__ f32x16 zero16() {
    f32x16 z;
    #pragma unroll
    for (int r = 0; r < 16; ++r) z[r] = 0.0f;
    return z;
}

// ---------------------------------------------------------------------------
// MFMA projection -> fragment-major Qf (alpha-scaled) and Vf.
// grid 256 = 4b x 64 n-tiles, block 256 (4 waves: 2 for Q, 2 for V).
// Both outputs re-staged through LDS in target layout, then coalesced copy.
// ---------------------------------------------------------------------------
template<int MODE>
__global__ __launch_bounds__(256) void proj_kernel(
    const float* __restrict__ xsrc,
    const float* __restrict__ Wq, const float* __restrict__ Bq,
    const float* __restrict__ Wv, const float* __restrict__ Bv,
    unsigned short* __restrict__ Qo, unsigned short* __restrict__ VTo)
{
    __shared__ __align__(16) unsigned short xbf[64 * 64];      // [n][d] XOR-swizzled
    __shared__ __align__(16) unsigned short wbf[2][64 * 64];   // [o][d] XOR-swizzled
    __shared__ __align__(16) unsigned short qst[4096];         // Q tile, frag layout
    __shared__ __align__(16) unsigned short vst[4096];         // V tile, frag layout

    const int b = blockIdx.x >> 6, tile = blockIdx.x & 63, n0 = tile << 6;
    const int tid = threadIdx.x;
    const float* xb = xsrc + b * BHWC;

    for (int i = tid; i < 4096; i += 256) {
        const int d = i >> 6, nl = i & 63;
        float v;
        if (MODE == 0) v = xb[d * 4096 + n0 + nl];
        else           v = xb[tile * 4096 + i];          // = tile*4096 + d*64 + c
        xbf[nl * 64 + (d ^ ((nl & 7) << 3))] = f2bf(v);
        wbf[0][d * 64 + (nl ^ ((d & 7) << 3))] = f2bf(Wq[i] * ALPHA);  // fold alpha
        wbf[1][d * 64 + (nl ^ ((d & 7) << 3))] = f2bf(Wv[i]);
    }
    __syncthreads();

    const int wave = tid >> 6, lane = tid & 63, l31 = lane & 31, hi = lane >> 5;
    const int mat = wave >> 1, nc = wave & 1;
    const int o = nc * 32 + l31;

    short8 bw[4];
    #pragma unroll
    for (int dc = 0; dc < 4; ++dc)
        bw[dc] = *(const short8*)&wbf[mat][o * 64 + ((dc * 16 + hi * 8) ^ ((o & 7) << 3))];

    f32x16 acc[2]; acc[0] = zero16(); acc[1] = zero16();
    #pragma unroll
    for (int dc = 0; dc < 4; ++dc) {
        #pragma unroll
        for (int mc = 0; mc < 2; ++mc) {
            const int row = mc * 32 + l31;
            const short8 a = *(const short8*)&xbf[row * 64 + ((dc * 16 + hi * 8) ^ ((row & 7) << 3))];
            acc[mc] = __builtin_amdgcn_mfma_f32_32x32x16_bf16(a, bw[dc], acc[mc], 0, 0, 0);
        }
    }
    const float bias = mat ? Bv[o] : (Bq[o] * ALPHA);

    if (mat == 0) {
        // Q[n][o] -> qst[mc*2048 + (o>>4)*512 + ((o>>3)&1)*256 + (nl&31)*8 + (o&7)]
        const int obase = ((o >> 4) << 9) + (((o >> 3) & 1) << 8) + (o & 7);
        #pragma unroll
        for (int mc = 0; mc < 2; ++mc)
            #pragma unroll
            for (int reg = 0; reg < 16; ++reg) {
                const int nl = (reg & 3) + 8 * (reg >> 2) + 4 * hi;
                qst[mc * 2048 + obase + nl * 8] = f2bf(acc[mc][reg] + bias);
            }
    } else {
        // V[n][o] -> vst[nc*2048 + (nl>>4)*512 + ((nl>>3)&1)*256 + l31*8 + (nl&7)]
        #pragma unroll
        for (int mc = 0; mc < 2; ++mc)
            #pragma unroll
            for (int reg = 0; reg < 16; ++reg) {
                const int nl = mc * 32 + (reg & 3) + 8 * (reg >> 2) + 4 * hi;
                vst[nc * 2048 + ((nl >> 4) << 9) + (((nl >> 3) & 1) << 8) + l31 * 8 + (nl & 7)]
                    = f2bf(acc[mc][reg] + bias);
            }
    }
    __syncthreads();

    {   // coalesced writeback: Q 8KB contiguous; V two 4KB regions
        unsigned short* Qg = Qo  + b * BHWC + tile * 4096;
        unsigned short* Vg = VTo + b * BHWC + tile * 2048;
        #pragma unroll
        for (int c = tid; c < 512; c += 256)
            *(u32x4*)(Qg + c * 8) = *(const u32x4*)(qst + c * 8);
        #pragma unroll
        for (int c = tid; c < 512; c += 256) {
            const int d0 = c >> 8, r = c & 255;
            *(u32x4*)(Vg + d0 * 131072 + r * 8) = *(const u32x4*)(vst + c * 8);
        }
    }
}

// ---------------------------------------------------------------------------
// Fused sigmoid-attention, 32x32 MFMA, fragment-major inputs (all global
// loads = 1KB contiguous per wave). P via per-wave-private LDS tiles with
// 144B row stride (bank-rotated, conflict-free, no XOR).
// grid 256 = 4b x 64 m-tiles; block 1024 = 16 waves = (msub 2) x (kq 8);
// wave tile = 32m x 512k, 8 iters of 64k. Barrier-free main loop.
// ---------------------------------------------------------------------------
template<int MODE>
__global__ __launch_bounds__(1024, 4) void attn_kernel(
    const unsigned short* __restrict__ Q,    // Qf layout, alpha-scaled (= K)
    const unsigned short* __restrict__ VT,   // Vf layout
    const float* __restrict__ xres,
    const float* __restrict__ wsc,
    float* __restrict__ xout)
{
    // union: Ps (16 waves x 32 rows x 144B = 73728B) / Obuf (8 x 2112 f32)
    __shared__ __align__(16) char smem[16 * 4608];
    float* Obuf = (float*)smem;

    const int bid = ((int)blockIdx.x & 7) * 32 + ((int)blockIdx.x >> 3);
    const int b = bid >> 6, mt = bid & 63, m0 = mt << 6;
    const int tid = threadIdx.x, wave = tid >> 6, lane = tid & 63;
    const int l31 = lane & 31, hi = lane >> 5;
    const int msub = wave & 1, kq = wave >> 1;
    const unsigned short* Qb = Q  + b * BHWC;
    const unsigned short* Vb = VT + b * BHWC;

    // P tile: rows at 144B stride (l31*9 mod 32 distinct banks per row)
    char* const Pw = smem + wave * 4608;
    char* const wb = Pw + l31 * 144 + 8 * hi;            // + krc*64 + 16*q
    const char* const pr = Pw + l31 * 144 + 16 * hi;     // + kc*32

    // Q B-fragments (persistent): lane-contiguous frag loads
    const unsigned short* qp = Qb + (mt * 2 + msub) * 2048 + hi * 256 + l31 * 8;
    short8 qf[4];
    #pragma unroll
    for (int dc = 0; dc < 4; ++dc)
        qf[dc] = *(const short8*)(qp + dc * 512);

    f32x16 acc[2]; acc[0] = zero16(); acc[1] = zero16();   // O[32m][64d]

    // sigmoid(S/8)=rcp(1+exp2(-S')); pack 4 consecutive kr -> b64 store
    auto SIGSTORE = [&](const f32x16& s, int krc) {
        #pragma unroll
        for (int q = 0; q < 4; ++q) {
            const float p0 = __builtin_amdgcn_rcpf(1.0f + exp2f(-s[4 * q    ]));
            const float p1 = __builtin_amdgcn_rcpf(1.0f + exp2f(-s[4 * q + 1]));
            const float p2 = __builtin_amdgcn_rcpf(1.0f + exp2f(-s[4 * q + 2]));
            const float p3 = __builtin_amdgcn_rcpf(1.0f + exp2f(-s[4 * q + 3]));
            u32x2 pk;
            pk[0] = (unsigned int)f2bf(p0) | ((unsigned int)f2bf(p1) << 16);
            pk[1] = (unsigned int)f2bf(p2) | ((unsigned int)f2bf(p3) << 16);
            *(u32x2*)(wb + krc * 64 + 16 * q) = pk;
        }
    };

    #pragma unroll 1
    for (int i = 0; i < 8; ++i) {
        const unsigned short* kp = Qb + (kq * 16 + i * 2) * 2048 + hi * 256 + l31 * 8;
        const unsigned short* vp = Vb + (kq * 32 + i * 4) * 512  + hi * 256 + l31 * 8;

        // ---- krc0: S^T[kr][m] = sum_d K[kr][d] Q[m][d] ----
        short8 kf[4];
        #pragma unroll
        for (int dc = 0; dc < 4; ++dc)
            kf[dc] = *(const short8*)(kp + dc * 512);
        f32x16 s = zero16();
        #pragma unroll
        for (int dc = 0; dc < 4; ++dc)
            s = __builtin_amdgcn_mfma_f32_32x32x16_bf16(kf[dc], qf[dc], s, 0, 0, 0);
        SIGSTORE(s, 0);

        // ---- krc1 (reuse kf/s regs) ----
        #pragma unroll
        for (int dc = 0; dc < 4; ++dc)
            kf[dc] = *(const short8*)(kp + 2048 + dc * 512);
        s = zero16();
        #pragma unroll
        for (int dc = 0; dc < 4; ++dc)
            s = __builtin_amdgcn_mfma_f32_32x32x16_bf16(kf[dc], qf[dc], s, 0, 0, 0);

        // first vf half (kc 0,1) issued before SIGSTORE: L2 latency hides
        short8 vf00 = *(const short8*)(vp + 0 * 512);
        short8 vf01 = *(const short8*)(vp + 0 * 512 + 131072);
        short8 vf10 = *(const short8*)(vp + 1 * 512);
        short8 vf11 = *(const short8*)(vp + 1 * 512 + 131072);

        SIGSTORE(s, 1);

        // ---- PV first half: kc 0,1 ----
        short8 pf0 = *(const short8*)(pr +  0);
        short8 pf1 = *(const short8*)(pr + 32);
        acc[0] = __builtin_amdgcn_mfma_f32_32x32x16_bf16(pf0, vf00, acc[0], 0, 0, 0);
        acc[1] = __builtin_amdgcn_mfma_f32_32x32x16_bf16(pf0, vf01, acc[1], 0, 0, 0);
        acc[0] = __builtin_amdgcn_mfma_f32_32x32x16_bf16(pf1, vf10, acc[0], 0, 0, 0);
        acc[1] = __builtin_amdgcn_mfma_f32_32x32x16_bf16(pf1, vf11, acc[1], 0, 0, 0);

        // ---- PV second half: kc 2,3 (reuse vf/pf regs) ----
        vf00 = *(const short8*)(vp + 2 * 512);
        vf01 = *(const short8*)(vp + 2 * 512 + 131072);
        vf10 = *(const short8*)(vp + 3 * 512);
        vf11 = *(const short8*)(vp + 3 * 512 + 131072);
        pf0 = *(const short8*)(pr + 64);
        pf1 = *(const short8*)(pr + 96);
        acc[0] = __builtin_amdgcn_mfma_f32_32x32x16_bf16(pf0, vf00, acc[0], 0, 0, 0);
        acc[1] = __builtin_amdgcn_mfma_f32_32x32x16_bf16(pf0, vf01, acc[1], 0, 0, 0);
        acc[0] = __builtin_amdgcn_mfma_f32_32x32x16_bf16(pf1, vf10, acc[0], 0, 0, 0);
        acc[1] = __builtin_amdgcn_mfma_f32_32x32x16_bf16(pf1, vf11, acc[1], 0, 0, 0);
    }

    // ---- tree-reduce 8 kq-partials per msub through LDS (aliases Ps) ----
    __syncthreads();
    if (kq < 4) {
        float* Ob = Obuf + (msub * 4 + kq) * 2112;
        #pragma unroll
        for (int dc2 = 0; dc2 < 2; ++dc2)
            #pragma unroll
            for (int reg = 0; reg < 16; ++reg)
                Ob[(dc2 * 32 + l31) * 33 + (reg & 3) + 8 * (reg >> 2) + 4 * hi] = acc[dc2][reg];
    }
    __syncthreads();
    if (kq >= 4) {
        float* Ob = Obuf + (msub * 4 + kq - 4) * 2112;
        #pragma unroll
        for (int dc2 = 0; dc2 < 2; ++dc2)
            #pragma unroll
            for (int reg = 0; reg < 16; ++reg)
                Ob[(dc2 * 32 + l31) * 33 + (reg & 3) + 8 * (reg >> 2) + 4 * hi] += acc[dc2][reg];
    }
    __syncthreads();

    // ---- epilogue: sum 4 slots + residual; 1024 threads x 4 outputs ----
    const float w = wsc[0];
    const int d = tid >> 4, ms = (tid & 15) << 2;
    const int msb = ms >> 5, mloc = ms & 31;
    long base;
    if (MODE == 0) base = (long)b * BHWC + d * 4096 + m0 + ms;
    else           base = (long)b * BHWC + mt * 4096 + d * 64 + ms;
    const float* O0 = Obuf + (msb * 4 + 0) * 2112 + d * 33 + mloc;
    const float* O1 = Obuf + (msb * 4 + 1) * 2112 + d * 33 + mloc;
    const float* O2 = Obuf + (msb * 4 + 2) * 2112 + d * 33 + mloc;
    const float* O3 = Obuf + (msb * 4 + 3) * 2112 + d * 33 + mloc;
    f32x4 r = *(const f32x4*)(xres + base);
    f32x4 o;
    #pragma unroll
    for (int j = 0; j < 4; ++j)
        o[j] = (O0[j] + O1[j] + O2[j] + O3[j]) * w + r[j];
    *(f32x4*)(xout + base) = o;
}

// ---------------------------------------------------------------------------
extern "C" void kernel_launch(void* const* d_in, const int* in_sizes, int n_in,
                              void* d_out, int out_size, void* d_ws, size_t ws_size,
                              hipStream_t stream) {
    const float* x    = (const float*)d_in[0];
    const float* hq_w = (const float*)d_in[1];
    const float* hq_b = (const float*)d_in[2];
    const float* hv_w = (const float*)d_in[3];
    const float* hv_b = (const float*)d_in[4];
    const float* wq_w = (const float*)d_in[5];
    const float* wq_b = (const float*)d_in[6];
    const float* wv_w = (const float*)d_in[7];
    const float* wv_b = (const float*)d_in[8];
    const float* h_wt = (const float*)d_in[9];
    const float* w_wt = (const float*)d_in[10];
    float* out = (float*)d_out;

    unsigned short* Qws  = (unsigned short*)d_ws;          // 2MB (Qf, alpha-scaled)
    unsigned short* VTws = Qws + 4 * BHWC;                 // 2MB (Vf)

    proj_kernel<0><<<256, 256, 0, stream>>>(x, hq_w, hq_b, hv_w, hv_b, Qws, VTws);
    attn_kernel<0><<<256, 1024, 0, stream>>>(Qws, VTws, x, h_wt, out);
    proj_kernel<1><<<256, 256, 0, stream>>>(out, wq_w, wq_b, wv_w, wv_b, Qws, VTws);
    attn_kernel<1><<<256, 1024, 0, stream>>>(Qws, VTws, out, w_wt, out);
}

// Round 8
// 76.538 us; speedup vs baseline: 1.8782x; 1.2853x over previous
//
#include <hip/hip_runtime.h>
#include <hip/hip_bf16.h>

// AxialAtten B=4,H=W=C=64. Two passes: Q=xW^T+b; K=Q; V=xWv^T+b;
// O = sigmoid(QK^T/8) V; x = O*scale + x (with axis transpose).
// Pass1: xh[b,n,d] = x[b*BHWC + d*4096 + n]            (n=w*64+c, d=h)
// Pass2: xw[b,n,d] = x[b*BHWC + (n>>6)*4096 + d*64 + (n&63)]  (d=w)
//
// Q pre-scaled by ALPHA = sqrt(0.125*log2(e)): sigmoid(S/8)=rcp(1+exp2(-S')).
//
// WORKSPACE LAYOUTS (fragment-major: every attn wave-load = 1KB contiguous):
//   Qf: element Q[n][d]  at b*BHWC + (n>>5)*2048 + (d>>4)*512 + ((d>>3)&1)*256
//                          + (n&31)*8 + (d&7)
//   Vf: element V^T[d][k] at b*BHWC + (d>>5)*131072 + (k>>4)*512 + ((k>>3)&1)*256
//                          + (d&31)*8 + (k&7)

typedef __attribute__((ext_vector_type(8)))  short        short8;   // 8 bf16
typedef __attribute__((ext_vector_type(16))) float        f32x16;
typedef __attribute__((ext_vector_type(4)))  unsigned int u32x4;
typedef __attribute__((ext_vector_type(2)))  unsigned int u32x2;
typedef __attribute__((ext_vector_type(4)))  float        f32x4;

#define BHWC (4096 * 64)
#define ALPHA 0.42466089f   // sqrt(0.125 * 1.44269504)

__device__ __forceinline__ unsigned short f2bf(float f) {
    __hip_bfloat16 h = __float2bfloat16(f);          // RNE
    union { __hip_bfloat16 h; unsigned short u; } c; c.h = h;
    return c.u;
}
// sigmoid(S/8) = rcp(1 + 2^(-S')) ; raw V_EXP/V_RCP (inputs bounded, no guards)
__device__ __forceinline__ float sigfast(float x) {
    float e, r;
    asm("v_exp_f32 %0, -%1" : "=v"(e) : "v"(x));
    e += 1.0f;
    asm("v_rcp_f32 %0, %1" : "=v"(r) : "v"(e));
    return r;
}
__device__ __forceinline__ f32x16 zero16() {
    f32x16 z;
    #pragma unroll
    for (int r = 0; r < 16; ++r) z[r] = 0.0f;
    return z;
}

// ---------------------------------------------------------------------------
// MFMA projection -> fragment-major Qf (alpha-scaled) and Vf. (unchanged r7)
// grid 256 = 4b x 64 n-tiles, block 256 (4 waves: 2 for Q, 2 for V).
// ---------------------------------------------------------------------------
template<int MODE>
__global__ __launch_bounds__(256) void proj_kernel(
    const float* __restrict__ xsrc,
    const float* __restrict__ Wq, const float* __restrict__ Bq,
    const float* __restrict__ Wv, const float* __restrict__ Bv,
    unsigned short* __restrict__ Qo, unsigned short* __restrict__ VTo)
{
    __shared__ __align__(16) unsigned short xbf[64 * 64];      // [n][d] XOR-swizzled
    __shared__ __align__(16) unsigned short wbf[2][64 * 64];   // [o][d] XOR-swizzled
    __shared__ __align__(16) unsigned short qst[4096];         // Q tile, frag layout
    __shared__ __align__(16) unsigned short vst[4096];         // V tile, frag layout

    const int b = blockIdx.x >> 6, tile = blockIdx.x & 63, n0 = tile << 6;
    const int tid = threadIdx.x;
    const float* xb = xsrc + b * BHWC;

    for (int i = tid; i < 4096; i += 256) {
        const int d = i >> 6, nl = i & 63;
        float v;
        if (MODE == 0) v = xb[d * 4096 + n0 + nl];
        else           v = xb[tile * 4096 + i];          // = tile*4096 + d*64 + c
        xbf[nl * 64 + (d ^ ((nl & 7) << 3))] = f2bf(v);
        wbf[0][d * 64 + (nl ^ ((d & 7) << 3))] = f2bf(Wq[i] * ALPHA);  // fold alpha
        wbf[1][d * 64 + (nl ^ ((d & 7) << 3))] = f2bf(Wv[i]);
    }
    __syncthreads();

    const int wave = tid >> 6, lane = tid & 63, l31 = lane & 31, hi = lane >> 5;
    const int mat = wave >> 1, nc = wave & 1;
    const int o = nc * 32 + l31;

    short8 bw[4];
    #pragma unroll
    for (int dc = 0; dc < 4; ++dc)
        bw[dc] = *(const short8*)&wbf[mat][o * 64 + ((dc * 16 + hi * 8) ^ ((o & 7) << 3))];

    f32x16 acc[2]; acc[0] = zero16(); acc[1] = zero16();
    #pragma unroll
    for (int dc = 0; dc < 4; ++dc) {
        #pragma unroll
        for (int mc = 0; mc < 2; ++mc) {
            const int row = mc * 32 + l31;
            const short8 a = *(const short8*)&xbf[row * 64 + ((dc * 16 + hi * 8) ^ ((row & 7) << 3))];
            acc[mc] = __builtin_amdgcn_mfma_f32_32x32x16_bf16(a, bw[dc], acc[mc], 0, 0, 0);
        }
    }
    const float bias = mat ? Bv[o] : (Bq[o] * ALPHA);

    if (mat == 0) {
        const int obase = ((o >> 4) << 9) + (((o >> 3) & 1) << 8) + (o & 7);
        #pragma unroll
        for (int mc = 0; mc < 2; ++mc)
            #pragma unroll
            for (int reg = 0; reg < 16; ++reg) {
                const int nl = (reg & 3) + 8 * (reg >> 2) + 4 * hi;
                qst[mc * 2048 + obase + nl * 8] = f2bf(acc[mc][reg] + bias);
            }
    } else {
        #pragma unroll
        for (int mc = 0; mc < 2; ++mc)
            #pragma unroll
            for (int reg = 0; reg < 16; ++reg) {
                const int nl = mc * 32 + (reg & 3) + 8 * (reg >> 2) + 4 * hi;
                vst[nc * 2048 + ((nl >> 4) << 9) + (((nl >> 3) & 1) << 8) + l31 * 8 + (nl & 7)]
                    = f2bf(acc[mc][reg] + bias);
            }
    }
    __syncthreads();

    {   // coalesced writeback: Q 8KB contiguous; V two 4KB regions
        unsigned short* Qg = Qo  + b * BHWC + tile * 4096;
        unsigned short* Vg = VTo + b * BHWC + tile * 2048;
        #pragma unroll
        for (int c = tid; c < 512; c += 256)
            *(u32x4*)(Qg + c * 8) = *(const u32x4*)(qst + c * 8);
        #pragma unroll
        for (int c = tid; c < 512; c += 256) {
            const int d0 = c >> 8, r = c & 255;
            *(u32x4*)(Vg + d0 * 131072 + r * 8) = *(const u32x4*)(vst + c * 8);
        }
    }
}

// ---------------------------------------------------------------------------
// Fused sigmoid-attention, 32x32 MFMA, fragment-major inputs.
// grid 512 = 4b x 128 m-tiles(32 rows); block 512 = 8 waves, wave kq owns
// k-slice [kq*512,(kq+1)*512), 8 iters of 64k -> 2 blocks/CU (4 waves/SIMD).
// P per-wave-private LDS (144B row stride, bank-rotated). Barrier-free loop.
// ---------------------------------------------------------------------------
template<int MODE>
__global__ __launch_bounds__(512, 4) void attn_kernel(
    const unsigned short* __restrict__ Q,    // Qf layout, alpha-scaled (= K)
    const unsigned short* __restrict__ VT,   // Vf layout
    const float* __restrict__ xres,
    const float* __restrict__ wsc,
    float* __restrict__ xout)
{
    // union: Ps (8 waves x 4608B = 36864B) / Obuf (4 x 64x33 f32 = 33792B)
    __shared__ __align__(16) char smem[8 * 4608];
    float* Obuf = (float*)smem;

    // XCD-contiguous: logical L = (raw&7)*64 + raw>>3 (64-block span per XCD)
    const int raw = (int)blockIdx.x;
    const int L = (raw & 7) * 64 + (raw >> 3);
    const int b = L >> 7, mt = L & 127;            // mt: 32-row m-tile
    const int tid = threadIdx.x, wave = tid >> 6, lane = tid & 63;
    const int l31 = lane & 31, hi = lane >> 5;
    const int kq = wave;                           // 8-way k split
    const unsigned short* Qb = Q  + b * BHWC;
    const unsigned short* Vb = VT + b * BHWC;

    // P tile: rows at 144B stride (9 coprime 32 -> bank-rotated, no XOR)
    char* const Pw = smem + wave * 4608;
    char* const wb = Pw + l31 * 144 + 8 * hi;            // + krc*64 + 16*q
    const char* const pr = Pw + l31 * 144 + 16 * hi;     // + kc*32

    // Q B-fragments (persistent): one contiguous 1KB wave-load per dc
    const unsigned short* qp = Qb + mt * 2048 + hi * 256 + l31 * 8;
    short8 qf[4];
    #pragma unroll
    for (int dc = 0; dc < 4; ++dc)
        qf[dc] = *(const short8*)(qp + dc * 512);

    f32x16 acc[2]; acc[0] = zero16(); acc[1] = zero16();   // O[32m][64d]

    auto SIGSTORE = [&](const f32x16& s, int krc) {
        #pragma unroll
        for (int q = 0; q < 4; ++q) {
            const float p0 = sigfast(s[4 * q    ]);
            const float p1 = sigfast(s[4 * q + 1]);
            const float p2 = sigfast(s[4 * q + 2]);
            const float p3 = sigfast(s[4 * q + 3]);
            u32x2 pk;
            pk[0] = (unsigned int)f2bf(p0) | ((unsigned int)f2bf(p1) << 16);
            pk[1] = (unsigned int)f2bf(p2) | ((unsigned int)f2bf(p3) << 16);
            *(u32x2*)(wb + krc * 64 + 16 * q) = pk;
        }
    };

    #pragma unroll 1
    for (int i = 0; i < 8; ++i) {
        const unsigned short* kp = Qb + (kq * 16 + i * 2) * 2048 + hi * 256 + l31 * 8;
        const unsigned short* vp = Vb + (kq * 32 + i * 4) * 512  + hi * 256 + l31 * 8;

        // ---- krc0: S^T[kr][m] = sum_d K[kr][d] Q[m][d] ----
        short8 kf[4];
        #pragma unroll
        for (int dc = 0; dc < 4; ++dc)
            kf[dc] = *(const short8*)(kp + dc * 512);
        f32x16 s = zero16();
        #pragma unroll
        for (int dc = 0; dc < 4; ++dc)
            s = __builtin_amdgcn_mfma_f32_32x32x16_bf16(kf[dc], qf[dc], s, 0, 0, 0);
        SIGSTORE(s, 0);

        // ---- krc1 (reuse kf/s regs) ----
        #pragma unroll
        for (int dc = 0; dc < 4; ++dc)
            kf[dc] = *(const short8*)(kp + 2048 + dc * 512);
        s = zero16();
        #pragma unroll
        for (int dc = 0; dc < 4; ++dc)
            s = __builtin_amdgcn_mfma_f32_32x32x16_bf16(kf[dc], qf[dc], s, 0, 0, 0);

        // first vf half (kc 0,1) issued before SIGSTORE: L2 latency hides
        short8 vf00 = *(const short8*)(vp + 0 * 512);
        short8 vf01 = *(const short8*)(vp + 0 * 512 + 131072);
        short8 vf10 = *(const short8*)(vp + 1 * 512);
        short8 vf11 = *(const short8*)(vp + 1 * 512 + 131072);

        SIGSTORE(s, 1);

        // ---- PV first half: kc 0,1 ----
        short8 pf0 = *(const short8*)(pr +  0);
        short8 pf1 = *(const short8*)(pr + 32);
        acc[0] = __builtin_amdgcn_mfma_f32_32x32x16_bf16(pf0, vf00, acc[0], 0, 0, 0);
        acc[1] = __builtin_amdgcn_mfma_f32_32x32x16_bf16(pf0, vf01, acc[1], 0, 0, 0);
        acc[0] = __builtin_amdgcn_mfma_f32_32x32x16_bf16(pf1, vf10, acc[0], 0, 0, 0);
        acc[1] = __builtin_amdgcn_mfma_f32_32x32x16_bf16(pf1, vf11, acc[1], 0, 0, 0);

        // ---- PV second half: kc 2,3 (reuse vf/pf regs) ----
        vf00 = *(const short8*)(vp + 2 * 512);
        vf01 = *(const short8*)(vp + 2 * 512 + 131072);
        vf10 = *(const short8*)(vp + 3 * 512);
        vf11 = *(const short8*)(vp + 3 * 512 + 131072);
        pf0 = *(const short8*)(pr + 64);
        pf1 = *(const short8*)(pr + 96);
        acc[0] = __builtin_amdgcn_mfma_f32_32x32x16_bf16(pf0, vf00, acc[0], 0, 0, 0);
        acc[1] = __builtin_amdgcn_mfma_f32_32x32x16_bf16(pf0, vf01, acc[1], 0, 0, 0);
        acc[0] = __builtin_amdgcn_mfma_f32_32x32x16_bf16(pf1, vf10, acc[0], 0, 0, 0);
        acc[1] = __builtin_amdgcn_mfma_f32_32x32x16_bf16(pf1, vf11, acc[1], 0, 0, 0);
    }

    // ---- tree-reduce 8 kq-partials through LDS (aliases Ps) ----
    __syncthreads();
    if (wave < 4) {
        float* Ob = Obuf + wave * 2112;
        #pragma unroll
        for (int dc2 = 0; dc2 < 2; ++dc2)
            #pragma unroll
            for (int reg = 0; reg < 16; ++reg)
                Ob[(dc2 * 32 + l31) * 33 + (reg & 3) + 8 * (reg >> 2) + 4 * hi] = acc[dc2][reg];
    }
    __syncthreads();
    if (wave >= 4) {
        float* Ob = Obuf + (wave - 4) * 2112;
        #pragma unroll
        for (int dc2 = 0; dc2 < 2; ++dc2)
            #pragma unroll
            for (int reg = 0; reg < 16; ++reg)
                Ob[(dc2 * 32 + l31) * 33 + (reg & 3) + 8 * (reg >> 2) + 4 * hi] += acc[dc2][reg];
    }
    __syncthreads();

    // ---- epilogue: sum 4 slots + residual; 512 threads x 4 outputs ----
    const float w = wsc[0];
    const int d = tid >> 3, ms = (tid & 7) << 2;
    long base;
    if (MODE == 0) base = (long)b * BHWC + d * 4096 + mt * 32 + ms;
    else           base = (long)b * BHWC + (mt >> 1) * 4096 + d * 64 + (mt & 1) * 32 + ms;
    const int idx = d * 33 + ms;
    const float* O0 = Obuf + 0 * 2112 + idx;
    const float* O1 = Obuf + 1 * 2112 + idx;
    const float* O2 = Obuf + 2 * 2112 + idx;
    const float* O3 = Obuf + 3 * 2112 + idx;
    f32x4 r = *(const f32x4*)(xres + base);
    f32x4 o;
    #pragma unroll
    for (int j = 0; j < 4; ++j)
        o[j] = (O0[j] + O1[j] + O2[j] + O3[j]) * w + r[j];
    *(f32x4*)(xout + base) = o;
}

// ---------------------------------------------------------------------------
extern "C" void kernel_launch(void* const* d_in, const int* in_sizes, int n_in,
                              void* d_out, int out_size, void* d_ws, size_t ws_size,
                              hipStream_t stream) {
    const float* x    = (const float*)d_in[0];
    const float* hq_w = (const float*)d_in[1];
    const float* hq_b = (const float*)d_in[2];
    const float* hv_w = (const float*)d_in[3];
    const float* hv_b = (const float*)d_in[4];
    const float* wq_w = (const float*)d_in[5];
    const float* wq_b = (const float*)d_in[6];
    const float* wv_w = (const float*)d_in[7];
    const float* wv_b = (const float*)d_in[8];
    const float* h_wt = (const float*)d_in[9];
    const float* w_wt = (const float*)d_in[10];
    float* out = (float*)d_out;

    unsigned short* Qws  = (unsigned short*)d_ws;          // 2MB (Qf, alpha-scaled)
    unsigned short* VTws = Qws + 4 * BHWC;                 // 2MB (Vf)

    proj_kernel<0><<<256, 256, 0, stream>>>(x, hq_w, hq_b, hv_w, hv_b, Qws, VTws);
    attn_kernel<0><<<512, 512, 0, stream>>>(Qws, VTws, x, h_wt, out);
    proj_kernel<1><<<256, 256, 0, stream>>>(out, wq_w, wq_b, wv_w, wv_b, Qws, VTws);
    attn_kernel<1><<<512, 512, 0, stream>>>(Qws, VTws, out, w_wt, out);
}